// Round 11
// baseline (275.476 us; speedup 1.0000x reference)
//
#include <hip/hip_runtime.h>
#include <hip/hip_bf16.h>

// b=2, t=4096, emb=512, heads=8, head_dim=64.
// out = softmax((xWq^T)(xWk^T)^T / sqrt(512)) (xWv^T) Wu^T + bu
// Round 10: NO-LDS attention. Per-tile K/V working set (8KB+8KB, shared by
// both co-resident blocks) is L1/L2-resident, so LDS staging + its 2
// barriers/tile were pure overhead (m169 precedent). kb/vb fragments now
// load directly from global with the same verified lane patterns; all LDS
// and all __syncthreads deleted; waves free-run. V re-blocked to
// [bh][tile][d][slot] so each V-tile is 8KB contiguous (L1-friendly).
// Register A/B prefetch pipeline for loads only. Keeps: swapped QK^T,
// C-in=-3, scale folded into Wq, in-register P, ell ones-MFMA, setprio.

#define T 4096
#define HEADS 8
#define HD 64
#define EMB 512
#define BATCH 2
#define BH (BATCH * HEADS)
#define NT (T / 64)

typedef __attribute__((ext_vector_type(8))) short short8;
typedef __attribute__((ext_vector_type(4))) float floatx4;

// f32 -> bf16 round-to-nearest-even
__device__ inline short f2bf(float f) {
  union { float f; unsigned u; } v; v.f = f;
  unsigned r = v.u + 0x7FFF + ((v.u >> 16) & 1);
  return (short)(r >> 16);
}

__device__ inline short8 pack8(float4 a, float4 b) {
  short8 o;
  o[0] = f2bf(a.x); o[1] = f2bf(a.y); o[2] = f2bf(a.z); o[3] = f2bf(a.w);
  o[4] = f2bf(b.x); o[5] = f2bf(b.y); o[6] = f2bf(b.z); o[7] = f2bf(b.w);
  return o;
}

// 8 floats -> short8 bf16 via compiler-generated v_cvt_pk_bf16_f32
__device__ inline short8 packbf(const float* p) {
  union { __hip_bfloat162 h[4]; short8 s; } u;
  float2 t;
  t.x = p[0]; t.y = p[1]; u.h[0] = __float22bfloat162_rn(t);
  t.x = p[2]; t.y = p[3]; u.h[1] = __float22bfloat162_rn(t);
  t.x = p[4]; t.y = p[5]; u.h[2] = __float22bfloat162_rn(t);
  t.x = p[6]; t.y = p[7]; u.h[3] = __float22bfloat162_rn(t);
  return u.s;
}

// swizzled byte offset in a [rows][64] bf16 tile (qkv/proj LDS only)
__device__ inline int swz(int row, int byte) {
  return (row * 128 + byte) ^ ((row & 7) << 4);
}

// ---------------------------------------------------------------------------
// Kernel A: q scaled by c2 (folded into Wq); k -> [bh][t][d];
// v -> vt[bh][tile][d][slot] (tile-blocked, 8KB contiguous per tile), slot =
// within-64 permuted: tp = (t&~31)|(((t>>2)&3)<<3)|(((t>>4)&1)<<2)|(t&3).
// ---------------------------------------------------------------------------
__global__ __launch_bounds__(256) void qkv_kernel(
    const float* __restrict__ x, const float* __restrict__ Wq,
    const float* __restrict__ Wk, const float* __restrict__ Wv,
    short* __restrict__ q_ws, short* __restrict__ k_ws, short* __restrict__ vt_ws) {
  __shared__ __align__(16) short xs[256 * 64];
  const int tid = threadIdx.x;
  const int lane = tid & 63;
  const int w = tid >> 6;
  const int g = lane >> 4, lr = lane & 15;
  const long rowbase = (long)blockIdx.x * 256;
  const float c2 = 0.0441941738241592f * 1.4426950408889634f;  // scale*log2e

  {
    const float4* xv = (const float4*)(x + (rowbase + tid) * 64);
    for (int c = 0; c < 8; ++c) {
      float4 a = xv[2 * c], b = xv[2 * c + 1];
      *(short8*)((char*)xs + swz(tid, c * 16)) = pack8(a, b);
    }
  }
  __syncthreads();

  const float* Ws[3] = {Wq, Wk, Wv};
  for (int m = 0; m < 3; ++m) {
    const float* W = Ws[m];
    const float sc = (m == 0) ? c2 : 1.0f;
    for (int nt = 0; nt < 4; ++nt) {
      const int coln = nt * 16 + lr;
      const float4* wr0 = (const float4*)(W + coln * 64 + 8 * g);
      const float4* wr1 = (const float4*)(W + coln * 64 + 32 + 8 * g);
      float4 w0 = wr0[0], w1 = wr0[1], w2 = wr1[0], w3 = wr1[1];
      w0.x *= sc; w0.y *= sc; w0.z *= sc; w0.w *= sc;
      w1.x *= sc; w1.y *= sc; w1.z *= sc; w1.w *= sc;
      w2.x *= sc; w2.y *= sc; w2.z *= sc; w2.w *= sc;
      w3.x *= sc; w3.y *= sc; w3.z *= sc; w3.w *= sc;
      short8 b0 = pack8(w0, w1);
      short8 b1 = pack8(w2, w3);
      for (int mr = 0; mr < 4; ++mr) {
        const int arow = w * 64 + mr * 16 + lr;
        short8 a0 = *(short8*)((char*)xs + swz(arow, g * 16));
        short8 a1 = *(short8*)((char*)xs + swz(arow, 64 + g * 16));
        floatx4 acc = 0;
        acc = __builtin_amdgcn_mfma_f32_16x16x32_bf16(a0, b0, acc, 0, 0, 0);
        acc = __builtin_amdgcn_mfma_f32_16x16x32_bf16(a1, b1, acc, 0, 0, 0);
        for (int jj = 0; jj < 4; ++jj) {
          long R = rowbase + w * 64 + mr * 16 + 4 * g + jj;
          int bb = (int)(R >> 15);
          int h = (int)(R & 7);
          int t = (int)((R >> 3) & 4095);
          if (m == 0)
            q_ws[(((long)(bb * HEADS + h) * T + t) * 64) + coln] = f2bf(acc[jj]);
          else if (m == 1)
            k_ws[(((long)(bb * HEADS + h) * T + t) * 64) + coln] = f2bf(acc[jj]);
          else {
            int tp = (t & ~31) | (((t >> 2) & 3) << 3) | (((t >> 4) & 1) << 2) | (t & 3);
            // tile-blocked: [bh][t>>6][d=coln][slot=tp&63]
            vt_ws[(((long)(bb * HEADS + h) * NT + (t >> 6)) * 64 + coln) * 64 + (tp & 63)] = f2bf(acc[jj]);
          }
        }
      }
    }
  }
}

// ---------------------------------------------------------------------------
// Kernel B: attention, zero LDS, zero barriers. 32 q-rows/wave, 128/block,
// grid 512. kb/vb fragments read directly from global (K tile and V tile are
// each 8KB contiguous -> L1/L2-resident, shared across co-resident blocks).
// A/B register prefetch: loads of tile i+1 issue before compute of tile i.
// ---------------------------------------------------------------------------
__global__ __launch_bounds__(256, 2) void attn_kernel(
    const short* __restrict__ q_ws, const short* __restrict__ k_ws,
    const short* __restrict__ vt_ws, short* __restrict__ o_ws) {
  const int tid = threadIdx.x, lane = tid & 63, w = tid >> 6;
  const int g = lane >> 4, lr = lane & 15;
  const int bh = blockIdx.y;
  const int q0 = blockIdx.x * 128;
  const short* Qp = q_ws + (long)bh * T * 64;
  const short* Kp = k_ws + (long)bh * T * 64;
  const short* Vt = vt_ws + (long)bh * T * 64;  // [tile][d][slot], 4096/tile

  short8 aq[2][2];
#pragma unroll
  for (int mt = 0; mt < 2; ++mt) {
    int r = q0 + w * 32 + mt * 16 + lr;
    aq[mt][0] = *(const short8*)(Qp + (long)r * 64 + g * 8);
    aq[mt][1] = *(const short8*)(Qp + (long)r * 64 + 32 + g * 8);
  }

  short8 one8;
#pragma unroll
  for (int e = 0; e < 8; ++e) one8[e] = (short)0x3F80;  // bf16 1.0

  floatx4 acc[2][4];   // [mt][dt]; rows = q_local 4g+j, cols = d dt*16+lr
  floatx4 acc_ell[2];  // [mt]; reg j = ell of row 4g+j
#pragma unroll
  for (int mt = 0; mt < 2; ++mt) {
    acc_ell[mt] = 0;
#pragma unroll
    for (int dt = 0; dt < 4; ++dt) acc[mt][dt] = 0;
  }

  short8 kbA[4][2], vbA[4][2], kbB[4][2], vbB[4][2];

#define LOADF(KV, kb, vb)                                                      \
  {                                                                            \
    const short* Kt_ = Kp + (long)(KV) * 64;                                   \
    const short* Vt_ = Vt + (long)(KV) * 64; /* tile*4096 == KV*64 */          \
    _Pragma("unroll")                                                          \
    for (int kt = 0; kt < 4; ++kt) {                                           \
      kb[kt][0] = *(const short8*)(Kt_ + (kt * 16 + lr) * 64 + g * 8);         \
      kb[kt][1] = *(const short8*)(Kt_ + (kt * 16 + lr) * 64 + 32 + g * 8);    \
    }                                                                          \
    _Pragma("unroll")                                                          \
    for (int dt = 0; dt < 4; ++dt) {                                           \
      vb[dt][0] = *(const short8*)(Vt_ + (dt * 16 + lr) * 64 + g * 8);         \
      vb[dt][1] = *(const short8*)(Vt_ + (dt * 16 + lr) * 64 + 32 + g * 8);    \
    }                                                                          \
  }

#define COMPUTE(kb, vb)                                                        \
  {                                                                            \
    _Pragma("unroll")                                                          \
    for (int mt = 0; mt < 2; ++mt) {                                           \
      floatx4 s[4];                                                            \
      __builtin_amdgcn_s_setprio(1);                                           \
      _Pragma("unroll")                                                        \
      for (int kt = 0; kt < 4; ++kt) {                                         \
        floatx4 z = {-3.f, -3.f, -3.f, -3.f};                                  \
        z = __builtin_amdgcn_mfma_f32_16x16x32_bf16(kb[kt][0], aq[mt][0], z, 0, 0, 0); \
        z = __builtin_amdgcn_mfma_f32_16x16x32_bf16(kb[kt][1], aq[mt][1], z, 0, 0, 0); \
        s[kt] = z;                                                             \
      }                                                                        \
      __builtin_amdgcn_s_setprio(0);                                           \
      float p[16];                                                             \
      _Pragma("unroll")                                                        \
      for (int kt = 0; kt < 4; ++kt)                                           \
        _Pragma("unroll")                                                      \
        for (int r = 0; r < 4; ++r)                                            \
          p[kt * 4 + r] = __builtin_amdgcn_exp2f(s[kt][r]);                    \
      short8 pa0 = packbf(p);                                                  \
      short8 pa1 = packbf(p + 8);                                              \
      __builtin_amdgcn_s_setprio(1);                                           \
      _Pragma("unroll")                                                        \
      for (int dt = 0; dt < 4; ++dt) {                                         \
        acc[mt][dt] = __builtin_amdgcn_mfma_f32_16x16x32_bf16(pa0, vb[dt][0], acc[mt][dt], 0, 0, 0); \
        acc[mt][dt] = __builtin_amdgcn_mfma_f32_16x16x32_bf16(pa1, vb[dt][1], acc[mt][dt], 0, 0, 0); \
      }                                                                        \
      acc_ell[mt] = __builtin_amdgcn_mfma_f32_16x16x32_bf16(pa0, one8, acc_ell[mt], 0, 0, 0); \
      acc_ell[mt] = __builtin_amdgcn_mfma_f32_16x16x32_bf16(pa1, one8, acc_ell[mt], 0, 0, 0); \
      __builtin_amdgcn_s_setprio(0);                                           \
    }                                                                          \
  }

  LOADF(0, kbA, vbA);
  for (int it = 0; it < NT; it += 2) {
    LOADF((((it + 1) & (NT - 1)) * 64), kbB, vbB);
    COMPUTE(kbA, vbA);
    LOADF((((it + 2) & (NT - 1)) * 64), kbA, vbA);
    COMPUTE(kbB, vbB);
  }
#undef LOADF
#undef COMPUTE

  // epilogue: rl per row directly from acc_ell
  const int bb = bh >> 3, h = bh & 7;
#pragma unroll
  for (int mt = 0; mt < 2; ++mt) {
#pragma unroll
    for (int j = 0; j < 4; ++j) {
      float rl = 1.0f / acc_ell[mt][j];
      int trow = q0 + w * 32 + mt * 16 + 4 * g + j;
      long ob = ((long)(bb * T + trow)) * EMB + h * 64;
#pragma unroll
      for (int dt = 0; dt < 4; ++dt)
        o_ws[ob + dt * 16 + lr] = f2bf(acc[mt][dt][j] * rl);
    }
  }
}

// ---------------------------------------------------------------------------
// Kernel C (verbatim): out[8192][512] = O @ Wu^T + bu (f32 out)
// ---------------------------------------------------------------------------
__global__ __launch_bounds__(256) void proj_kernel(
    const short* __restrict__ o_ws, const float* __restrict__ Wu,
    const float* __restrict__ bu, float* __restrict__ out) {
  __shared__ __align__(16) short As[64 * 64];
  __shared__ __align__(16) short Bs[64 * 64];
  const int tid = threadIdx.x;
  const int lane = tid & 63, w = tid >> 6;
  const int g = lane >> 4, lr = lane & 15;
  const int m0 = blockIdx.x * 64;
  const int n0 = blockIdx.y * 64;

  floatx4 acc[4];
  for (int nt = 0; nt < 4; ++nt) acc[nt] = 0;

  for (int kc = 0; kc < EMB; kc += 64) {
    {
      int row = tid >> 2, kp = (tid & 3) * 16;
      const short8* src = (const short8*)(o_ws + (long)(m0 + row) * EMB + kc + kp);
      short8 v0 = src[0], v1 = src[1];
      *(short8*)((char*)As + swz(row, kp * 2)) = v0;
      *(short8*)((char*)As + swz(row, kp * 2 + 16)) = v1;
    }
    {
      int n = tid >> 2, kp = (tid & 3) * 16;
      const float4* src = (const float4*)(Wu + (long)(n0 + n) * EMB + kc + kp);
      *(short8*)((char*)Bs + swz(n, kp * 2)) = pack8(src[0], src[1]);
      *(short8*)((char*)Bs + swz(n, kp * 2 + 16)) = pack8(src[2], src[3]);
    }
    __syncthreads();

    int arow = w * 16 + lr;
    short8 a0 = *(short8*)((char*)As + swz(arow, g * 16));
    short8 a1 = *(short8*)((char*)As + swz(arow, 64 + g * 16));
    for (int nt = 0; nt < 4; ++nt) {
      int n = nt * 16 + lr;
      short8 b0 = *(short8*)((char*)Bs + swz(n, g * 16));
      short8 b1 = *(short8*)((char*)Bs + swz(n, 64 + g * 16));
      acc[nt] = __builtin_amdgcn_mfma_f32_16x16x32_bf16(a0, b0, acc[nt], 0, 0, 0);
      acc[nt] = __builtin_amdgcn_mfma_f32_16x16x32_bf16(a1, b1, acc[nt], 0, 0, 0);
    }
    __syncthreads();
  }

  for (int nt = 0; nt < 4; ++nt) {
    float bias = bu[n0 + nt * 16 + lr];
    for (int j = 0; j < 4; ++j) {
      int mrow = m0 + w * 16 + 4 * g + j;
      out[(long)mrow * EMB + n0 + nt * 16 + lr] = acc[nt][j] + bias;
    }
  }
}

extern "C" void kernel_launch(void* const* d_in, const int* in_sizes, int n_in,
                              void* d_out, int out_size, void* d_ws, size_t ws_size,
                              hipStream_t stream) {
  const float* x  = (const float*)d_in[0];
  const float* Wq = (const float*)d_in[1];
  const float* Wk = (const float*)d_in[2];
  const float* Wv = (const float*)d_in[3];
  const float* Wu = (const float*)d_in[4];
  const float* bu = (const float*)d_in[5];
  float* out = (float*)d_out;

  const long per = (long)BH * T * 64;
  short* q_ws  = (short*)d_ws;
  short* k_ws  = q_ws + per;
  short* vt_ws = k_ws + per;   // [bh][tile][d][slot], 4096 elems per tile
  short* o_ws  = vt_ws + per;  // [8192][512] bf16

  qkv_kernel<<<256, 256, 0, stream>>>(x, Wq, Wk, Wv, q_ws, k_ws, vt_ws);
  attn_kernel<<<dim3(T / 128, BH), 256, 0, stream>>>(q_ws, k_ws, vt_ws, o_ws);
  proj_kernel<<<dim3(BATCH * T / 64, EMB / 64), 256, 0, stream>>>(o_ws, Wu, bu, out);
}

// Round 12
// 135.245 us; speedup vs baseline: 2.0369x; 2.0369x over previous
//
#include <hip/hip_runtime.h>
#include <hip/hip_bf16.h>

// b=2, t=4096, emb=512, heads=8, head_dim=64.
// out = softmax((xWq^T)(xWk^T)^T / sqrt(512)) (xWv^T) Wu^T + bu
// Round 11: revert attn/qkv to round-7 exact (95us attn; round-10 no-LDS
// regressed 2.4x: without LDS, 8 waves/CU re-read 128KB/tile through L1 —
// staging IS the de-duplication). Round-9's ell-ones-MFMA identified as its
// +6us regression; dropped. New: proj widened to 64x128 tiles (8 col-tiles
// per wave -> 8x a-fragment reuse, 2x MFMA:staging ratio).

#define T 4096
#define HEADS 8
#define HD 64
#define EMB 512
#define BATCH 2
#define BH (BATCH * HEADS)
#define NT (T / 64)

typedef __attribute__((ext_vector_type(8))) short short8;
typedef __attribute__((ext_vector_type(4))) float floatx4;

// f32 -> bf16 round-to-nearest-even
__device__ inline short f2bf(float f) {
  union { float f; unsigned u; } v; v.f = f;
  unsigned r = v.u + 0x7FFF + ((v.u >> 16) & 1);
  return (short)(r >> 16);
}

__device__ inline short8 pack8(float4 a, float4 b) {
  short8 o;
  o[0] = f2bf(a.x); o[1] = f2bf(a.y); o[2] = f2bf(a.z); o[3] = f2bf(a.w);
  o[4] = f2bf(b.x); o[5] = f2bf(b.y); o[6] = f2bf(b.z); o[7] = f2bf(b.w);
  return o;
}

// 8 floats -> short8 bf16 via compiler-generated v_cvt_pk_bf16_f32
__device__ inline short8 packbf(const float* p) {
  union { __hip_bfloat162 h[4]; short8 s; } u;
  float2 t;
  t.x = p[0]; t.y = p[1]; u.h[0] = __float22bfloat162_rn(t);
  t.x = p[2]; t.y = p[3]; u.h[1] = __float22bfloat162_rn(t);
  t.x = p[4]; t.y = p[5]; u.h[2] = __float22bfloat162_rn(t);
  t.x = p[6]; t.y = p[7]; u.h[3] = __float22bfloat162_rn(t);
  return u.s;
}

// swizzled byte offset in a [rows][64] bf16 tile (row stride 128B)
__device__ inline int swz(int row, int byte) {
  return (row * 128 + byte) ^ ((row & 7) << 4);
}

// ---------------------------------------------------------------------------
// Kernel A (round-7 verbatim): q,k -> [bh][t][d]; v -> vt[bh][d][t''] with
// t'' = (t&~31)|((t>>2)&3)<<3|((t>>4)&1)<<2|(t&3) (PV slot order).
// ---------------------------------------------------------------------------
__global__ __launch_bounds__(256) void qkv_kernel(
    const float* __restrict__ x, const float* __restrict__ Wq,
    const float* __restrict__ Wk, const float* __restrict__ Wv,
    short* __restrict__ q_ws, short* __restrict__ k_ws, short* __restrict__ vt_ws) {
  __shared__ __align__(16) short xs[256 * 64];
  const int tid = threadIdx.x;
  const int lane = tid & 63;
  const int w = tid >> 6;
  const int g = lane >> 4, lr = lane & 15;
  const long rowbase = (long)blockIdx.x * 256;

  {
    const float4* xv = (const float4*)(x + (rowbase + tid) * 64);
    for (int c = 0; c < 8; ++c) {
      float4 a = xv[2 * c], b = xv[2 * c + 1];
      *(short8*)((char*)xs + swz(tid, c * 16)) = pack8(a, b);
    }
  }
  __syncthreads();

  const float* Ws[3] = {Wq, Wk, Wv};
  for (int m = 0; m < 3; ++m) {
    const float* W = Ws[m];
    for (int nt = 0; nt < 4; ++nt) {
      const int coln = nt * 16 + lr;
      const float4* wr0 = (const float4*)(W + coln * 64 + 8 * g);
      const float4* wr1 = (const float4*)(W + coln * 64 + 32 + 8 * g);
      short8 b0 = pack8(wr0[0], wr0[1]);
      short8 b1 = pack8(wr1[0], wr1[1]);
      for (int mr = 0; mr < 4; ++mr) {
        const int arow = w * 64 + mr * 16 + lr;
        short8 a0 = *(short8*)((char*)xs + swz(arow, g * 16));
        short8 a1 = *(short8*)((char*)xs + swz(arow, 64 + g * 16));
        floatx4 acc = 0;
        acc = __builtin_amdgcn_mfma_f32_16x16x32_bf16(a0, b0, acc, 0, 0, 0);
        acc = __builtin_amdgcn_mfma_f32_16x16x32_bf16(a1, b1, acc, 0, 0, 0);
        for (int jj = 0; jj < 4; ++jj) {
          long R = rowbase + w * 64 + mr * 16 + 4 * g + jj;
          int bb = (int)(R >> 15);
          int h = (int)(R & 7);
          int t = (int)((R >> 3) & 4095);
          if (m == 0)
            q_ws[(((long)(bb * HEADS + h) * T + t) * 64) + coln] = f2bf(acc[jj]);
          else if (m == 1)
            k_ws[(((long)(bb * HEADS + h) * T + t) * 64) + coln] = f2bf(acc[jj]);
          else {
            int tp = (t & ~31) | (((t >> 2) & 3) << 3) | (((t >> 4) & 1) << 2) | (t & 3);
            vt_ws[((long)(bb * HEADS + h) * 64 + coln) * T + tp] = f2bf(acc[jj]);
          }
        }
      }
    }
  }
}

// ---------------------------------------------------------------------------
// Kernel B (round-7 verbatim): attention. 32 q-rows/wave, 128/block, grid 512.
// Swapped QK^T -> lane (g,lr) holds S[q=lr][keys 16kt+4g+reg]. exp2 in-reg,
// pack to pa0/pa1 (PV A-fragments, slot order p=8g+4kt+reg), PV directly.
// Ks/Vs double-buffered, ONE barrier per iteration. No P LDS buffer.
// ---------------------------------------------------------------------------
__global__ __launch_bounds__(256) void attn_kernel(
    const short* __restrict__ q_ws, const short* __restrict__ k_ws,
    const short* __restrict__ vt_ws, short* __restrict__ o_ws) {
  __shared__ __align__(16) short Ks[2][64 * 64];    // [key][d] swizzled
  __shared__ __align__(16) short Vs[2][64 * 64];    // [d][key-slot] swizzled
  const int tid = threadIdx.x, lane = tid & 63, w = tid >> 6;
  const int g = lane >> 4, lr = lane & 15;
  const int bh = blockIdx.y;
  const int q0 = blockIdx.x * 128;
  const short* Qp = q_ws + (long)bh * T * 64;
  const short* Kp = k_ws + (long)bh * T * 64;
  const short* Vt = vt_ws + (long)bh * 64 * T;

  const float c2 = 0.0441941738241592f * 1.4426950408889634f;  // scale * log2(e)

  short8 aq[2][2];
#pragma unroll
  for (int mt = 0; mt < 2; ++mt) {
    int r = q0 + w * 32 + mt * 16 + lr;
    aq[mt][0] = *(const short8*)(Qp + (long)r * 64 + g * 8);
    aq[mt][1] = *(const short8*)(Qp + (long)r * 64 + 32 + g * 8);
  }

  floatx4 acc[2][4];  // [mt][dt]; rows = q_local 4g+j, cols = d dt*16+lr
#pragma unroll
  for (int mt = 0; mt < 2; ++mt)
#pragma unroll
    for (int dt = 0; dt < 4; ++dt) acc[mt][dt] = 0;
  float ellp[2] = {0.f, 0.f};

  const int srow = tid >> 2;          // 0..63
  const int sseg = (tid & 3) * 16;    // element offset in row

  // prologue: stage tile 0 into buffer 0
  {
    const short8* ksrc = (const short8*)(Kp + (long)srow * 64 + sseg);
    short8 k0 = ksrc[0], k1 = ksrc[1];
    const short8* vsrc = (const short8*)(Vt + (long)srow * T + sseg);
    short8 v0 = vsrc[0], v1 = vsrc[1];
    *(short8*)((char*)Ks[0] + swz(srow, sseg * 2)) = k0;
    *(short8*)((char*)Ks[0] + swz(srow, sseg * 2 + 16)) = k1;
    *(short8*)((char*)Vs[0] + swz(srow, sseg * 2)) = v0;
    *(short8*)((char*)Vs[0] + swz(srow, sseg * 2 + 16)) = v1;
  }
  __syncthreads();

  for (int it = 0; it < NT; ++it) {
    const int cur = it & 1;
    const int nk = ((it + 1) & (NT - 1)) * 64;
    const short8* ksrc = (const short8*)(Kp + (long)(nk + srow) * 64 + sseg);
    short8 nk0 = ksrc[0], nk1 = ksrc[1];
    const short8* vsrc = (const short8*)(Vt + (long)srow * T + nk + sseg);
    short8 nv0 = vsrc[0], nv1 = vsrc[1];

    const char* KsB = (const char*)Ks[cur];
    const char* VsB = (const char*)Vs[cur];

    short8 kb[4][2], vb[4][2];
#pragma unroll
    for (int kt = 0; kt < 4; ++kt) {
      kb[kt][0] = *(const short8*)(KsB + swz(kt * 16 + lr, g * 16));
      kb[kt][1] = *(const short8*)(KsB + swz(kt * 16 + lr, 64 + g * 16));
    }
#pragma unroll
    for (int dt = 0; dt < 4; ++dt) {
      vb[dt][0] = *(const short8*)(VsB + swz(dt * 16 + lr, g * 16));
      vb[dt][1] = *(const short8*)(VsB + swz(dt * 16 + lr, 64 + g * 16));
    }

#pragma unroll
    for (int mt = 0; mt < 2; ++mt) {
      floatx4 s[4];
#pragma unroll
      for (int kt = 0; kt < 4; ++kt) {
        floatx4 z = 0;
        z = __builtin_amdgcn_mfma_f32_16x16x32_bf16(kb[kt][0], aq[mt][0], z, 0, 0, 0);
        z = __builtin_amdgcn_mfma_f32_16x16x32_bf16(kb[kt][1], aq[mt][1], z, 0, 0, 0);
        s[kt] = z;
      }
      float p[16];
#pragma unroll
      for (int kt = 0; kt < 4; ++kt)
#pragma unroll
        for (int r = 0; r < 4; ++r)
          p[kt * 4 + r] = __builtin_amdgcn_exp2f(fmaf(s[kt][r], c2, -3.0f));
#pragma unroll
      for (int e = 0; e < 16; ++e) ellp[mt] += p[e];
      short8 pa0 = packbf(p);
      short8 pa1 = packbf(p + 8);
#pragma unroll
      for (int dt = 0; dt < 4; ++dt) {
        acc[mt][dt] = __builtin_amdgcn_mfma_f32_16x16x32_bf16(pa0, vb[dt][0], acc[mt][dt], 0, 0, 0);
        acc[mt][dt] = __builtin_amdgcn_mfma_f32_16x16x32_bf16(pa1, vb[dt][1], acc[mt][dt], 0, 0, 0);
      }
    }

    // write prefetched tile to the other buffer
    char* KsN = (char*)Ks[cur ^ 1];
    char* VsN = (char*)Vs[cur ^ 1];
    *(short8*)(KsN + swz(srow, sseg * 2)) = nk0;
    *(short8*)(KsN + swz(srow, sseg * 2 + 16)) = nk1;
    *(short8*)(VsN + swz(srow, sseg * 2)) = nv0;
    *(short8*)(VsN + swz(srow, sseg * 2 + 16)) = nv1;
    __syncthreads();
  }

  // epilogue: reduce ellp across g-groups, normalize, store
  float ef[2];
#pragma unroll
  for (int mt = 0; mt < 2; ++mt) {
    float e = ellp[mt];
    e += __shfl_xor(e, 16);
    e += __shfl_xor(e, 32);
    ef[mt] = e;
  }
  const int bb = bh >> 3, h = bh & 7;
#pragma unroll
  for (int mt = 0; mt < 2; ++mt) {
#pragma unroll
    for (int j = 0; j < 4; ++j) {
      float rl = 1.0f / __shfl(ef[mt], 4 * g + j);
      int trow = q0 + w * 32 + mt * 16 + 4 * g + j;
      long ob = ((long)(bb * T + trow)) * EMB + h * 64;
#pragma unroll
      for (int dt = 0; dt < 4; ++dt)
        o_ws[ob + dt * 16 + lr] = f2bf(acc[mt][dt][j] * rl);
    }
  }
}

// ---------------------------------------------------------------------------
// Kernel C: out[8192][512] = O @ Wu^T + bu (f32 out). 64x128 block tiles:
// each wave computes 16 rows x 128 cols (8 col-tiles) -> 8x a-frag reuse.
// ---------------------------------------------------------------------------
__global__ __launch_bounds__(256) void proj_kernel(
    const short* __restrict__ o_ws, const float* __restrict__ Wu,
    const float* __restrict__ bu, float* __restrict__ out) {
  __shared__ __align__(16) short As[64 * 64];    // [row][k] swizzled (8KB)
  __shared__ __align__(16) short Bs[128 * 64];   // [n][k] swizzled (16KB)
  const int tid = threadIdx.x;
  const int lane = tid & 63, w = tid >> 6;
  const int g = lane >> 4, lr = lane & 15;
  const int m0 = blockIdx.x * 64;
  const int n0 = blockIdx.y * 128;

  floatx4 acc[8];
#pragma unroll
  for (int nt = 0; nt < 8; ++nt) acc[nt] = 0;

  for (int kc = 0; kc < EMB; kc += 64) {
    {
      int row = tid >> 2, kp = (tid & 3) * 16;
      const short8* src = (const short8*)(o_ws + (long)(m0 + row) * EMB + kc + kp);
      short8 v0 = src[0], v1 = src[1];
      *(short8*)((char*)As + swz(row, kp * 2)) = v0;
      *(short8*)((char*)As + swz(row, kp * 2 + 16)) = v1;
    }
#pragma unroll
    for (int nn = 0; nn < 2; ++nn) {
      int n = nn * 64 + (tid >> 2), kp = (tid & 3) * 16;
      const float4* src = (const float4*)(Wu + (long)(n0 + n) * EMB + kc + kp);
      *(short8*)((char*)Bs + swz(n, kp * 2)) = pack8(src[0], src[1]);
      *(short8*)((char*)Bs + swz(n, kp * 2 + 16)) = pack8(src[2], src[3]);
    }
    __syncthreads();

    int arow = w * 16 + lr;
    short8 a0 = *(short8*)((char*)As + swz(arow, g * 16));
    short8 a1 = *(short8*)((char*)As + swz(arow, 64 + g * 16));
#pragma unroll
    for (int nt = 0; nt < 8; ++nt) {
      int n = nt * 16 + lr;
      short8 b0 = *(short8*)((char*)Bs + swz(n, g * 16));
      short8 b1 = *(short8*)((char*)Bs + swz(n, 64 + g * 16));
      acc[nt] = __builtin_amdgcn_mfma_f32_16x16x32_bf16(a0, b0, acc[nt], 0, 0, 0);
      acc[nt] = __builtin_amdgcn_mfma_f32_16x16x32_bf16(a1, b1, acc[nt], 0, 0, 0);
    }
    __syncthreads();
  }

#pragma unroll
  for (int nt = 0; nt < 8; ++nt) {
    float bias = bu[n0 + nt * 16 + lr];
#pragma unroll
    for (int j = 0; j < 4; ++j) {
      int mrow = m0 + w * 16 + 4 * g + j;
      out[(long)mrow * EMB + n0 + nt * 16 + lr] = acc[nt][j] + bias;
    }
  }
}

extern "C" void kernel_launch(void* const* d_in, const int* in_sizes, int n_in,
                              void* d_out, int out_size, void* d_ws, size_t ws_size,
                              hipStream_t stream) {
  const float* x  = (const float*)d_in[0];
  const float* Wq = (const float*)d_in[1];
  const float* Wk = (const float*)d_in[2];
  const float* Wv = (const float*)d_in[3];
  const float* Wu = (const float*)d_in[4];
  const float* bu = (const float*)d_in[5];
  float* out = (float*)d_out;

  const long per = (long)BH * T * 64;
  short* q_ws  = (short*)d_ws;
  short* k_ws  = q_ws + per;
  short* vt_ws = k_ws + per;   // [bh][d][t''] (key-permuted within 32-blocks)
  short* o_ws  = vt_ws + per;  // [8192][512] bf16

  qkv_kernel<<<256, 256, 0, stream>>>(x, Wq, Wk, Wv, q_ws, k_ws, vt_ws);
  attn_kernel<<<dim3(T / 128, BH), 256, 0, stream>>>(q_ws, k_ws, vt_ws, o_ws);
  proj_kernel<<<dim3(BATCH * T / 64, EMB / 128), 256, 0, stream>>>(o_ws, Wu, bu, out);
}

// Round 13
// 132.657 us; speedup vs baseline: 2.0766x; 1.0195x over previous
//
#include <hip/hip_runtime.h>
#include <hip/hip_bf16.h>

// b=2, t=4096, emb=512, heads=8, head_dim=64.
// out = softmax((xWq^T)(xWk^T)^T / sqrt(512)) (xWv^T) Wu^T + bu
// Round 12: attn byte-identical to round 7/11 (95us, proven). qkv reworked:
// swapped-mfma (proven trick) -> lane holds 4 consecutive cols -> short4 LDS
// gather (barriered, short-typed) -> coalesced 16B global stores (was 192
// scalar 2B stores/thread); 128-row blocks, grid 512 = 2/CU. proj: swapped
// mfma -> float4 epilogue stores + vectorized bias (was 32 scalar stores).

#define T 4096
#define HEADS 8
#define HD 64
#define EMB 512
#define BATCH 2
#define BH (BATCH * HEADS)
#define NT (T / 64)

typedef __attribute__((ext_vector_type(8))) short short8;
typedef __attribute__((ext_vector_type(4))) short short4v;
typedef __attribute__((ext_vector_type(4))) float floatx4;

// f32 -> bf16 round-to-nearest-even
__device__ inline short f2bf(float f) {
  union { float f; unsigned u; } v; v.f = f;
  unsigned r = v.u + 0x7FFF + ((v.u >> 16) & 1);
  return (short)(r >> 16);
}

__device__ inline short8 pack8(float4 a, float4 b) {
  short8 o;
  o[0] = f2bf(a.x); o[1] = f2bf(a.y); o[2] = f2bf(a.z); o[3] = f2bf(a.w);
  o[4] = f2bf(b.x); o[5] = f2bf(b.y); o[6] = f2bf(b.z); o[7] = f2bf(b.w);
  return o;
}

// 8 floats -> short8 bf16 via compiler-generated v_cvt_pk_bf16_f32
__device__ inline short8 packbf(const float* p) {
  union { __hip_bfloat162 h[4]; short8 s; } u;
  float2 t;
  t.x = p[0]; t.y = p[1]; u.h[0] = __float22bfloat162_rn(t);
  t.x = p[2]; t.y = p[3]; u.h[1] = __float22bfloat162_rn(t);
  t.x = p[4]; t.y = p[5]; u.h[2] = __float22bfloat162_rn(t);
  t.x = p[6]; t.y = p[7]; u.h[3] = __float22bfloat162_rn(t);
  return u.s;
}

// swizzled byte offset in a [rows][64] bf16 tile (row stride 128B)
__device__ inline int swz(int row, int byte) {
  return (row * 128 + byte) ^ ((row & 7) << 4);
}

// ---------------------------------------------------------------------------
// Kernel A: q,k -> [bh][t][d]; v -> vt[bh][d][t''] with
// t'' = (t&~31)|((t>>2)&3)<<3|((t>>4)&1)<<2|(t&3) (PV slot order).
// Swapped mfma: C[coln][t] -> lane holds 4 consecutive coln of one row.
// q/k: short4 -> LDS gather -> coalesced 16B stores. v: 4-scalar scatter.
// 128 rows/block, grid 512 (2 blocks/CU).
// ---------------------------------------------------------------------------
__global__ __launch_bounds__(256) void qkv_kernel(
    const float* __restrict__ x, const float* __restrict__ Wq,
    const float* __restrict__ Wk, const float* __restrict__ Wv,
    short* __restrict__ q_ws, short* __restrict__ k_ws, short* __restrict__ vt_ws) {
  __shared__ __align__(16) short xs[128 * 64];  // staged x (bf16)
  __shared__ __align__(16) short ob[128 * 64];  // output gather buffer
  const int tid = threadIdx.x;
  const int lane = tid & 63;
  const int w = tid >> 6;
  const int g = lane >> 4, lr = lane & 15;
  const long rowbase = (long)blockIdx.x * 128;

  // stage 128 rows of x as bf16 (2 threads/row, 64B each)
  {
    int row = tid >> 1, hf = tid & 1;
    const float4* xv = (const float4*)(x + (rowbase + row) * 64 + hf * 32);
#pragma unroll
    for (int c = 0; c < 4; ++c) {
      float4 a = xv[2 * c], b = xv[2 * c + 1];
      *(short8*)((char*)xs + swz(row, hf * 64 + c * 16)) = pack8(a, b);
    }
  }
  __syncthreads();

  const float* Ws[3] = {Wq, Wk, Wv};
  for (int m = 0; m < 3; ++m) {
    const float* W = Ws[m];
    for (int nt = 0; nt < 4; ++nt) {
      // A-operand: W[row=nt*16+lr][k=8g+j] (same pack as proven rounds)
      const int coln_a = nt * 16 + lr;
      const float4* wr0 = (const float4*)(W + coln_a * 64 + 8 * g);
      const float4* wr1 = (const float4*)(W + coln_a * 64 + 32 + 8 * g);
      short8 b0 = pack8(wr0[0], wr0[1]);
      short8 b1 = pack8(wr1[0], wr1[1]);
      for (int mr = 0; mr < 2; ++mr) {
        const int arow = w * 32 + mr * 16 + lr;
        short8 a0 = *(short8*)((char*)xs + swz(arow, g * 16));
        short8 a1 = *(short8*)((char*)xs + swz(arow, 64 + g * 16));
        floatx4 acc = 0;
        // swapped: A = W frag, B = x frag -> C[coln][t]
        acc = __builtin_amdgcn_mfma_f32_16x16x32_bf16(b0, a0, acc, 0, 0, 0);
        acc = __builtin_amdgcn_mfma_f32_16x16x32_bf16(b1, a1, acc, 0, 0, 0);
        if (m < 2) {
          // lane holds coln = nt*16+4g+{0..3} for local row w*32+mr*16+lr
          short4v pk;
          pk[0] = f2bf(acc[0]); pk[1] = f2bf(acc[1]);
          pk[2] = f2bf(acc[2]); pk[3] = f2bf(acc[3]);
          *(short4v*)((char*)ob + swz(w * 32 + mr * 16 + lr, 32 * nt + 8 * g)) = pk;
        } else {
          long R = rowbase + w * 32 + mr * 16 + lr;
          int bb = (int)(R >> 15);
          int h = (int)(R & 7);
          int t = (int)((R >> 3) & 4095);
          int tp = (t & ~31) | (((t >> 2) & 3) << 3) | (((t >> 4) & 1) << 2) | (t & 3);
#pragma unroll
          for (int jj = 0; jj < 4; ++jj) {
            int coln = nt * 16 + 4 * g + jj;
            vt_ws[((long)(bb * HEADS + h) * 64 + coln) * T + tp] = f2bf(acc[jj]);
          }
        }
      }
    }
    if (m < 2) {
      short* dst_ws = (m == 0) ? q_ws : k_ws;
      __syncthreads();  // all ob writes done
      {
        int row = tid >> 1, hf = tid & 1;
        long R = rowbase + row;
        int bb = (int)(R >> 15);
        int h = (int)(R & 7);
        int t = (int)((R >> 3) & 4095);
        short* dst = dst_ws + ((long)(bb * HEADS + h) * T + t) * 64 + hf * 32;
#pragma unroll
        for (int c = 0; c < 4; ++c) {
          short8 v = *(short8*)((char*)ob + swz(row, hf * 64 + c * 16));
          *(short8*)(dst + c * 8) = v;
        }
      }
      __syncthreads();  // readout done before next matrix overwrites ob
    }
  }
}

// ---------------------------------------------------------------------------
// Kernel B (round-7 verbatim): attention. 32 q-rows/wave, 128/block, grid 512.
// Swapped QK^T -> lane (g,lr) holds S[q=lr][keys 16kt+4g+reg]. exp2 in-reg,
// pack to pa0/pa1 (PV A-fragments, slot order p=8g+4kt+reg), PV directly.
// Ks/Vs double-buffered, ONE barrier per iteration. No P LDS buffer.
// ---------------------------------------------------------------------------
__global__ __launch_bounds__(256) void attn_kernel(
    const short* __restrict__ q_ws, const short* __restrict__ k_ws,
    const short* __restrict__ vt_ws, short* __restrict__ o_ws) {
  __shared__ __align__(16) short Ks[2][64 * 64];    // [key][d] swizzled
  __shared__ __align__(16) short Vs[2][64 * 64];    // [d][key-slot] swizzled
  const int tid = threadIdx.x, lane = tid & 63, w = tid >> 6;
  const int g = lane >> 4, lr = lane & 15;
  const int bh = blockIdx.y;
  const int q0 = blockIdx.x * 128;
  const short* Qp = q_ws + (long)bh * T * 64;
  const short* Kp = k_ws + (long)bh * T * 64;
  const short* Vt = vt_ws + (long)bh * 64 * T;

  const float c2 = 0.0441941738241592f * 1.4426950408889634f;  // scale * log2(e)

  short8 aq[2][2];
#pragma unroll
  for (int mt = 0; mt < 2; ++mt) {
    int r = q0 + w * 32 + mt * 16 + lr;
    aq[mt][0] = *(const short8*)(Qp + (long)r * 64 + g * 8);
    aq[mt][1] = *(const short8*)(Qp + (long)r * 64 + 32 + g * 8);
  }

  floatx4 acc[2][4];  // [mt][dt]; rows = q_local 4g+j, cols = d dt*16+lr
#pragma unroll
  for (int mt = 0; mt < 2; ++mt)
#pragma unroll
    for (int dt = 0; dt < 4; ++dt) acc[mt][dt] = 0;
  float ellp[2] = {0.f, 0.f};

  const int srow = tid >> 2;          // 0..63
  const int sseg = (tid & 3) * 16;    // element offset in row

  // prologue: stage tile 0 into buffer 0
  {
    const short8* ksrc = (const short8*)(Kp + (long)srow * 64 + sseg);
    short8 k0 = ksrc[0], k1 = ksrc[1];
    const short8* vsrc = (const short8*)(Vt + (long)srow * T + sseg);
    short8 v0 = vsrc[0], v1 = vsrc[1];
    *(short8*)((char*)Ks[0] + swz(srow, sseg * 2)) = k0;
    *(short8*)((char*)Ks[0] + swz(srow, sseg * 2 + 16)) = k1;
    *(short8*)((char*)Vs[0] + swz(srow, sseg * 2)) = v0;
    *(short8*)((char*)Vs[0] + swz(srow, sseg * 2 + 16)) = v1;
  }
  __syncthreads();

  for (int it = 0; it < NT; ++it) {
    const int cur = it & 1;
    const int nk = ((it + 1) & (NT - 1)) * 64;
    const short8* ksrc = (const short8*)(Kp + (long)(nk + srow) * 64 + sseg);
    short8 nk0 = ksrc[0], nk1 = ksrc[1];
    const short8* vsrc = (const short8*)(Vt + (long)srow * T + nk + sseg);
    short8 nv0 = vsrc[0], nv1 = vsrc[1];

    const char* KsB = (const char*)Ks[cur];
    const char* VsB = (const char*)Vs[cur];

    short8 kb[4][2], vb[4][2];
#pragma unroll
    for (int kt = 0; kt < 4; ++kt) {
      kb[kt][0] = *(const short8*)(KsB + swz(kt * 16 + lr, g * 16));
      kb[kt][1] = *(const short8*)(KsB + swz(kt * 16 + lr, 64 + g * 16));
    }
#pragma unroll
    for (int dt = 0; dt < 4; ++dt) {
      vb[dt][0] = *(const short8*)(VsB + swz(dt * 16 + lr, g * 16));
      vb[dt][1] = *(const short8*)(VsB + swz(dt * 16 + lr, 64 + g * 16));
    }

#pragma unroll
    for (int mt = 0; mt < 2; ++mt) {
      floatx4 s[4];
#pragma unroll
      for (int kt = 0; kt < 4; ++kt) {
        floatx4 z = 0;
        z = __builtin_amdgcn_mfma_f32_16x16x32_bf16(kb[kt][0], aq[mt][0], z, 0, 0, 0);
        z = __builtin_amdgcn_mfma_f32_16x16x32_bf16(kb[kt][1], aq[mt][1], z, 0, 0, 0);
        s[kt] = z;
      }
      float p[16];
#pragma unroll
      for (int kt = 0; kt < 4; ++kt)
#pragma unroll
        for (int r = 0; r < 4; ++r)
          p[kt * 4 + r] = __builtin_amdgcn_exp2f(fmaf(s[kt][r], c2, -3.0f));
#pragma unroll
      for (int e = 0; e < 16; ++e) ellp[mt] += p[e];
      short8 pa0 = packbf(p);
      short8 pa1 = packbf(p + 8);
#pragma unroll
      for (int dt = 0; dt < 4; ++dt) {
        acc[mt][dt] = __builtin_amdgcn_mfma_f32_16x16x32_bf16(pa0, vb[dt][0], acc[mt][dt], 0, 0, 0);
        acc[mt][dt] = __builtin_amdgcn_mfma_f32_16x16x32_bf16(pa1, vb[dt][1], acc[mt][dt], 0, 0, 0);
      }
    }

    // write prefetched tile to the other buffer
    char* KsN = (char*)Ks[cur ^ 1];
    char* VsN = (char*)Vs[cur ^ 1];
    *(short8*)(KsN + swz(srow, sseg * 2)) = nk0;
    *(short8*)(KsN + swz(srow, sseg * 2 + 16)) = nk1;
    *(short8*)(VsN + swz(srow, sseg * 2)) = nv0;
    *(short8*)(VsN + swz(srow, sseg * 2 + 16)) = nv1;
    __syncthreads();
  }

  // epilogue: reduce ellp across g-groups, normalize, store
  float ef[2];
#pragma unroll
  for (int mt = 0; mt < 2; ++mt) {
    float e = ellp[mt];
    e += __shfl_xor(e, 16);
    e += __shfl_xor(e, 32);
    ef[mt] = e;
  }
  const int bb = bh >> 3, h = bh & 7;
#pragma unroll
  for (int mt = 0; mt < 2; ++mt) {
#pragma unroll
    for (int j = 0; j < 4; ++j) {
      float rl = 1.0f / __shfl(ef[mt], 4 * g + j);
      int trow = q0 + w * 32 + mt * 16 + 4 * g + j;
      long ob2 = ((long)(bb * T + trow)) * EMB + h * 64;
#pragma unroll
      for (int dt = 0; dt < 4; ++dt)
        o_ws[ob2 + dt * 16 + lr] = f2bf(acc[mt][dt][j] * rl);
    }
  }
}

// ---------------------------------------------------------------------------
// Kernel C: out[8192][512] = O @ Wu^T + bu (f32 out). 64x128 tiles, swapped
// mfma -> lane holds 4 consecutive n of one row -> float4 stores.
// ---------------------------------------------------------------------------
__global__ __launch_bounds__(256) void proj_kernel(
    const short* __restrict__ o_ws, const float* __restrict__ Wu,
    const float* __restrict__ bu, float* __restrict__ out) {
  __shared__ __align__(16) short As[64 * 64];    // [row][k] swizzled (8KB)
  __shared__ __align__(16) short Bs[128 * 64];   // [n][k] swizzled (16KB)
  const int tid = threadIdx.x;
  const int lane = tid & 63, w = tid >> 6;
  const int g = lane >> 4, lr = lane & 15;
  const int m0 = blockIdx.x * 64;
  const int n0 = blockIdx.y * 128;

  floatx4 acc[8];
#pragma unroll
  for (int nt = 0; nt < 8; ++nt) acc[nt] = 0;

  for (int kc = 0; kc < EMB; kc += 64) {
    {
      int row = tid >> 2, kp = (tid & 3) * 16;
      const short8* src = (const short8*)(o_ws + (long)(m0 + row) * EMB + kc + kp);
      short8 v0 = src[0], v1 = src[1];
      *(short8*)((char*)As + swz(row, kp * 2)) = v0;
      *(short8*)((char*)As + swz(row, kp * 2 + 16)) = v1;
    }
#pragma unroll
    for (int nn = 0; nn < 2; ++nn) {
      int n = nn * 64 + (tid >> 2), kp = (tid & 3) * 16;
      const float4* src = (const float4*)(Wu + (long)(n0 + n) * EMB + kc + kp);
      *(short8*)((char*)Bs + swz(n, kp * 2)) = pack8(src[0], src[1]);
      *(short8*)((char*)Bs + swz(n, kp * 2 + 16)) = pack8(src[2], src[3]);
    }
    __syncthreads();

    int arow = w * 16 + lr;
    short8 a0 = *(short8*)((char*)As + swz(arow, g * 16));
    short8 a1 = *(short8*)((char*)As + swz(arow, 64 + g * 16));
#pragma unroll
    for (int nt = 0; nt < 8; ++nt) {
      int n = nt * 16 + lr;
      short8 b0 = *(short8*)((char*)Bs + swz(n, g * 16));
      short8 b1 = *(short8*)((char*)Bs + swz(n, 64 + g * 16));
      // swapped: C[n][m] -> lane holds n = nt*16+4g+{0..3}, m = w*16+lr
      acc[nt] = __builtin_amdgcn_mfma_f32_16x16x32_bf16(b0, a0, acc[nt], 0, 0, 0);
      acc[nt] = __builtin_amdgcn_mfma_f32_16x16x32_bf16(b1, a1, acc[nt], 0, 0, 0);
    }
    __syncthreads();
  }

  const int mrow = m0 + w * 16 + lr;
#pragma unroll
  for (int nt = 0; nt < 8; ++nt) {
    float4 bias = *(const float4*)(bu + n0 + nt * 16 + 4 * g);
    float4 o;
    o.x = acc[nt][0] + bias.x;
    o.y = acc[nt][1] + bias.y;
    o.z = acc[nt][2] + bias.z;
    o.w = acc[nt][3] + bias.w;
    *(float4*)(out + (long)mrow * EMB + n0 + nt * 16 + 4 * g) = o;
  }
}

extern "C" void kernel_launch(void* const* d_in, const int* in_sizes, int n_in,
                              void* d_out, int out_size, void* d_ws, size_t ws_size,
                              hipStream_t stream) {
  const float* x  = (const float*)d_in[0];
  const float* Wq = (const float*)d_in[1];
  const float* Wk = (const float*)d_in[2];
  const float* Wv = (const float*)d_in[3];
  const float* Wu = (const float*)d_in[4];
  const float* bu = (const float*)d_in[5];
  float* out = (float*)d_out;

  const long per = (long)BH * T * 64;
  short* q_ws  = (short*)d_ws;
  short* k_ws  = q_ws + per;
  short* vt_ws = k_ws + per;   // [bh][d][t''] (key-permuted within 32-blocks)
  short* o_ws  = vt_ws + per;  // [8192][512] bf16

  qkv_kernel<<<512, 256, 0, stream>>>(x, Wq, Wk, Wv, q_ws, k_ws, vt_ws);
  attn_kernel<<<dim3(T / 128, BH), 256, 0, stream>>>(q_ws, k_ws, vt_ws, o_ws);
  proj_kernel<<<dim3(BATCH * T / 64, EMB / 128), 256, 0, stream>>>(o_ws, Wu, bu, out);
}

// Round 14
// 128.793 us; speedup vs baseline: 2.1389x; 1.0300x over previous
//
#include <hip/hip_runtime.h>
#include <hip/hip_bf16.h>

// b=2, t=4096, emb=512, heads=8, head_dim=64.
// out = softmax((xWq^T)(xWk^T)^T / sqrt(512)) (xWv^T) Wu^T + bu
// Round 13: (1) all bf16 packing via __float22bfloat162_rn (hw cvt_pk, 1 op
// per 2 elems) replacing the 4-5-op f2bf bit trick in qkv/proj staging —
// qkv was spending ~600 VALU ops/thread on rounding. (2) attn: scale folded
// into Wq + QK^T C-in=-3 -> p=exp2(s) direct (kills 32 fmaf/thread/tile);
// this piece alone from passing round 9 (its ell-MFMA regression dropped).
// attn structure otherwise byte-identical to round 7 (95us proven).

#define T 4096
#define HEADS 8
#define HD 64
#define EMB 512
#define BATCH 2
#define BH (BATCH * HEADS)
#define NT (T / 64)

typedef __attribute__((ext_vector_type(8))) short short8;
typedef __attribute__((ext_vector_type(4))) short short4v;
typedef __attribute__((ext_vector_type(4))) float floatx4;

// f32 -> bf16 RNE (scalar; epilogue/scatter only)
__device__ inline short f2bf(float f) {
  union { float f; unsigned u; } v; v.f = f;
  unsigned r = v.u + 0x7FFF + ((v.u >> 16) & 1);
  return (short)(r >> 16);
}

// 8 f32 -> 8 bf16 via hw v_cvt_pk_bf16_f32 (4 instructions)
__device__ inline short8 pack8(float4 a, float4 b) {
  union { __hip_bfloat162 h[4]; short8 s; } u;
  float2 t;
  t.x = a.x; t.y = a.y; u.h[0] = __float22bfloat162_rn(t);
  t.x = a.z; t.y = a.w; u.h[1] = __float22bfloat162_rn(t);
  t.x = b.x; t.y = b.y; u.h[2] = __float22bfloat162_rn(t);
  t.x = b.z; t.y = b.w; u.h[3] = __float22bfloat162_rn(t);
  return u.s;
}

// 4 f32 -> 4 bf16 (2 instructions)
__device__ inline short4v pack4(floatx4 a) {
  union { __hip_bfloat162 h[2]; short4v s; } u;
  float2 t;
  t.x = a[0]; t.y = a[1]; u.h[0] = __float22bfloat162_rn(t);
  t.x = a[2]; t.y = a[3]; u.h[1] = __float22bfloat162_rn(t);
  return u.s;
}

// 8 floats -> short8 bf16 (P fragments)
__device__ inline short8 packbf(const float* p) {
  union { __hip_bfloat162 h[4]; short8 s; } u;
  float2 t;
  t.x = p[0]; t.y = p[1]; u.h[0] = __float22bfloat162_rn(t);
  t.x = p[2]; t.y = p[3]; u.h[1] = __float22bfloat162_rn(t);
  t.x = p[4]; t.y = p[5]; u.h[2] = __float22bfloat162_rn(t);
  t.x = p[6]; t.y = p[7]; u.h[3] = __float22bfloat162_rn(t);
  return u.s;
}

// swizzled byte offset in a [rows][64] bf16 tile (row stride 128B)
__device__ inline int swz(int row, int byte) {
  return (row * 128 + byte) ^ ((row & 7) << 4);
}

// ---------------------------------------------------------------------------
// Kernel A: q (scaled by c2=log2e/sqrt(512), folded into Wq pack), k ->
// [bh][t][d]; v -> vt[bh][d][t''], t''=(t&~31)|((t>>2)&3)<<3|((t>>4)&1)<<2|(t&3).
// Swapped mfma -> lane holds 4 consecutive coln; q/k gathered via LDS to
// coalesced 16B stores. 128 rows/block, grid 512.
// ---------------------------------------------------------------------------
__global__ __launch_bounds__(256) void qkv_kernel(
    const float* __restrict__ x, const float* __restrict__ Wq,
    const float* __restrict__ Wk, const float* __restrict__ Wv,
    short* __restrict__ q_ws, short* __restrict__ k_ws, short* __restrict__ vt_ws) {
  __shared__ __align__(16) short xs[128 * 64];  // staged x (bf16)
  __shared__ __align__(16) short ob[128 * 64];  // output gather buffer
  const int tid = threadIdx.x;
  const int lane = tid & 63;
  const int w = tid >> 6;
  const int g = lane >> 4, lr = lane & 15;
  const long rowbase = (long)blockIdx.x * 128;
  const float c2 = 0.0441941738241592f * 1.4426950408889634f;

  // stage 128 rows of x as bf16 (2 threads/row, 64B each)
  {
    int row = tid >> 1, hf = tid & 1;
    const float4* xv = (const float4*)(x + (rowbase + row) * 64 + hf * 32);
#pragma unroll
    for (int c = 0; c < 4; ++c) {
      float4 a = xv[2 * c], b = xv[2 * c + 1];
      *(short8*)((char*)xs + swz(row, hf * 64 + c * 16)) = pack8(a, b);
    }
  }
  __syncthreads();

  const float* Ws[3] = {Wq, Wk, Wv};
  for (int m = 0; m < 3; ++m) {
    const float* W = Ws[m];
    const float sc = (m == 0) ? c2 : 1.0f;
    for (int nt = 0; nt < 4; ++nt) {
      const int coln_a = nt * 16 + lr;
      const float4* wr0 = (const float4*)(W + coln_a * 64 + 8 * g);
      const float4* wr1 = (const float4*)(W + coln_a * 64 + 32 + 8 * g);
      float4 w0 = wr0[0], w1 = wr0[1], w2 = wr1[0], w3 = wr1[1];
      w0.x *= sc; w0.y *= sc; w0.z *= sc; w0.w *= sc;
      w1.x *= sc; w1.y *= sc; w1.z *= sc; w1.w *= sc;
      w2.x *= sc; w2.y *= sc; w2.z *= sc; w2.w *= sc;
      w3.x *= sc; w3.y *= sc; w3.z *= sc; w3.w *= sc;
      short8 b0 = pack8(w0, w1);
      short8 b1 = pack8(w2, w3);
      for (int mr = 0; mr < 2; ++mr) {
        const int arow = w * 32 + mr * 16 + lr;
        short8 a0 = *(short8*)((char*)xs + swz(arow, g * 16));
        short8 a1 = *(short8*)((char*)xs + swz(arow, 64 + g * 16));
        floatx4 acc = 0;
        // swapped: A = W frag, B = x frag -> C[coln][t]
        acc = __builtin_amdgcn_mfma_f32_16x16x32_bf16(b0, a0, acc, 0, 0, 0);
        acc = __builtin_amdgcn_mfma_f32_16x16x32_bf16(b1, a1, acc, 0, 0, 0);
        if (m < 2) {
          *(short4v*)((char*)ob + swz(w * 32 + mr * 16 + lr, 32 * nt + 8 * g)) = pack4(acc);
        } else {
          long R = rowbase + w * 32 + mr * 16 + lr;
          int bb = (int)(R >> 15);
          int h = (int)(R & 7);
          int t = (int)((R >> 3) & 4095);
          int tp = (t & ~31) | (((t >> 2) & 3) << 3) | (((t >> 4) & 1) << 2) | (t & 3);
          short4v pk = pack4(acc);
#pragma unroll
          for (int jj = 0; jj < 4; ++jj) {
            int coln = nt * 16 + 4 * g + jj;
            vt_ws[((long)(bb * HEADS + h) * 64 + coln) * T + tp] = pk[jj];
          }
        }
      }
    }
    if (m < 2) {
      short* dst_ws = (m == 0) ? q_ws : k_ws;
      __syncthreads();  // all ob writes done
      {
        int row = tid >> 1, hf = tid & 1;
        long R = rowbase + row;
        int bb = (int)(R >> 15);
        int h = (int)(R & 7);
        int t = (int)((R >> 3) & 4095);
        short* dst = dst_ws + ((long)(bb * HEADS + h) * T + t) * 64 + hf * 32;
#pragma unroll
        for (int c = 0; c < 4; ++c) {
          short8 v = *(short8*)((char*)ob + swz(row, hf * 64 + c * 16));
          *(short8*)(dst + c * 8) = v;
        }
      }
      __syncthreads();  // readout done before next matrix overwrites ob
    }
  }
}

// ---------------------------------------------------------------------------
// Kernel B: attention (round-7 structure). Swapped QK^T with C-in=-3 and
// scale pre-folded into q -> p = exp2(s) direct. In-register P, per-lane ell,
// Ks/Vs double-buffered, ONE barrier per iteration.
// ---------------------------------------------------------------------------
__global__ __launch_bounds__(256) void attn_kernel(
    const short* __restrict__ q_ws, const short* __restrict__ k_ws,
    const short* __restrict__ vt_ws, short* __restrict__ o_ws) {
  __shared__ __align__(16) short Ks[2][64 * 64];    // [key][d] swizzled
  __shared__ __align__(16) short Vs[2][64 * 64];    // [d][key-slot] swizzled
  const int tid = threadIdx.x, lane = tid & 63, w = tid >> 6;
  const int g = lane >> 4, lr = lane & 15;
  const int bh = blockIdx.y;
  const int q0 = blockIdx.x * 128;
  const short* Qp = q_ws + (long)bh * T * 64;
  const short* Kp = k_ws + (long)bh * T * 64;
  const short* Vt = vt_ws + (long)bh * 64 * T;

  short8 aq[2][2];
#pragma unroll
  for (int mt = 0; mt < 2; ++mt) {
    int r = q0 + w * 32 + mt * 16 + lr;
    aq[mt][0] = *(const short8*)(Qp + (long)r * 64 + g * 8);
    aq[mt][1] = *(const short8*)(Qp + (long)r * 64 + 32 + g * 8);
  }

  floatx4 acc[2][4];  // [mt][dt]; rows = q_local 4g+j, cols = d dt*16+lr
#pragma unroll
  for (int mt = 0; mt < 2; ++mt)
#pragma unroll
    for (int dt = 0; dt < 4; ++dt) acc[mt][dt] = 0;
  float ellp[2] = {0.f, 0.f};

  const int srow = tid >> 2;          // 0..63
  const int sseg = (tid & 3) * 16;    // element offset in row

  // prologue: stage tile 0 into buffer 0
  {
    const short8* ksrc = (const short8*)(Kp + (long)srow * 64 + sseg);
    short8 k0 = ksrc[0], k1 = ksrc[1];
    const short8* vsrc = (const short8*)(Vt + (long)srow * T + sseg);
    short8 v0 = vsrc[0], v1 = vsrc[1];
    *(short8*)((char*)Ks[0] + swz(srow, sseg * 2)) = k0;
    *(short8*)((char*)Ks[0] + swz(srow, sseg * 2 + 16)) = k1;
    *(short8*)((char*)Vs[0] + swz(srow, sseg * 2)) = v0;
    *(short8*)((char*)Vs[0] + swz(srow, sseg * 2 + 16)) = v1;
  }
  __syncthreads();

  for (int it = 0; it < NT; ++it) {
    const int cur = it & 1;
    const int nk = ((it + 1) & (NT - 1)) * 64;
    const short8* ksrc = (const short8*)(Kp + (long)(nk + srow) * 64 + sseg);
    short8 nk0 = ksrc[0], nk1 = ksrc[1];
    const short8* vsrc = (const short8*)(Vt + (long)srow * T + nk + sseg);
    short8 nv0 = vsrc[0], nv1 = vsrc[1];

    const char* KsB = (const char*)Ks[cur];
    const char* VsB = (const char*)Vs[cur];

    short8 kb[4][2], vb[4][2];
#pragma unroll
    for (int kt = 0; kt < 4; ++kt) {
      kb[kt][0] = *(const short8*)(KsB + swz(kt * 16 + lr, g * 16));
      kb[kt][1] = *(const short8*)(KsB + swz(kt * 16 + lr, 64 + g * 16));
    }
#pragma unroll
    for (int dt = 0; dt < 4; ++dt) {
      vb[dt][0] = *(const short8*)(VsB + swz(dt * 16 + lr, g * 16));
      vb[dt][1] = *(const short8*)(VsB + swz(dt * 16 + lr, 64 + g * 16));
    }

#pragma unroll
    for (int mt = 0; mt < 2; ++mt) {
      floatx4 s[4];
#pragma unroll
      for (int kt = 0; kt < 4; ++kt) {
        floatx4 z = {-3.f, -3.f, -3.f, -3.f};  // softmax bias via C-in
        z = __builtin_amdgcn_mfma_f32_16x16x32_bf16(kb[kt][0], aq[mt][0], z, 0, 0, 0);
        z = __builtin_amdgcn_mfma_f32_16x16x32_bf16(kb[kt][1], aq[mt][1], z, 0, 0, 0);
        s[kt] = z;
      }
      float p[16];
#pragma unroll
      for (int kt = 0; kt < 4; ++kt)
#pragma unroll
        for (int r = 0; r < 4; ++r)
          p[kt * 4 + r] = __builtin_amdgcn_exp2f(s[kt][r]);  // scale pre-folded
#pragma unroll
      for (int e = 0; e < 16; ++e) ellp[mt] += p[e];
      short8 pa0 = packbf(p);
      short8 pa1 = packbf(p + 8);
#pragma unroll
      for (int dt = 0; dt < 4; ++dt) {
        acc[mt][dt] = __builtin_amdgcn_mfma_f32_16x16x32_bf16(pa0, vb[dt][0], acc[mt][dt], 0, 0, 0);
        acc[mt][dt] = __builtin_amdgcn_mfma_f32_16x16x32_bf16(pa1, vb[dt][1], acc[mt][dt], 0, 0, 0);
      }
    }

    // write prefetched tile to the other buffer
    char* KsN = (char*)Ks[cur ^ 1];
    char* VsN = (char*)Vs[cur ^ 1];
    *(short8*)(KsN + swz(srow, sseg * 2)) = nk0;
    *(short8*)(KsN + swz(srow, sseg * 2 + 16)) = nk1;
    *(short8*)(VsN + swz(srow, sseg * 2)) = nv0;
    *(short8*)(VsN + swz(srow, sseg * 2 + 16)) = nv1;
    __syncthreads();
  }

  // epilogue: reduce ellp across g-groups, normalize, store
  float ef[2];
#pragma unroll
  for (int mt = 0; mt < 2; ++mt) {
    float e = ellp[mt];
    e += __shfl_xor(e, 16);
    e += __shfl_xor(e, 32);
    ef[mt] = e;
  }
  const int bb = bh >> 3, h = bh & 7;
#pragma unroll
  for (int mt = 0; mt < 2; ++mt) {
#pragma unroll
    for (int j = 0; j < 4; ++j) {
      float rl = 1.0f / __shfl(ef[mt], 4 * g + j);
      int trow = q0 + w * 32 + mt * 16 + 4 * g + j;
      long ob2 = ((long)(bb * T + trow)) * EMB + h * 64;
#pragma unroll
      for (int dt = 0; dt < 4; ++dt)
        o_ws[ob2 + dt * 16 + lr] = f2bf(acc[mt][dt][j] * rl);
    }
  }
}

// ---------------------------------------------------------------------------
// Kernel C: out[8192][512] = O @ Wu^T + bu (f32 out). 64x128 tiles, swapped
// mfma -> lane holds 4 consecutive n of one row -> float4 stores.
// ---------------------------------------------------------------------------
__global__ __launch_bounds__(256) void proj_kernel(
    const short* __restrict__ o_ws, const float* __restrict__ Wu,
    const float* __restrict__ bu, float* __restrict__ out) {
  __shared__ __align__(16) short As[64 * 64];    // [row][k] swizzled (8KB)
  __shared__ __align__(16) short Bs[128 * 64];   // [n][k] swizzled (16KB)
  const int tid = threadIdx.x;
  const int lane = tid & 63, w = tid >> 6;
  const int g = lane >> 4, lr = lane & 15;
  const int m0 = blockIdx.x * 64;
  const int n0 = blockIdx.y * 128;

  floatx4 acc[8];
#pragma unroll
  for (int nt = 0; nt < 8; ++nt) acc[nt] = 0;

  for (int kc = 0; kc < EMB; kc += 64) {
    {
      int row = tid >> 2, kp = (tid & 3) * 16;
      const short8* src = (const short8*)(o_ws + (long)(m0 + row) * EMB + kc + kp);
      short8 v0 = src[0], v1 = src[1];
      *(short8*)((char*)As + swz(row, kp * 2)) = v0;
      *(short8*)((char*)As + swz(row, kp * 2 + 16)) = v1;
    }
#pragma unroll
    for (int nn = 0; nn < 2; ++nn) {
      int n = nn * 64 + (tid >> 2), kp = (tid & 3) * 16;
      const float4* src = (const float4*)(Wu + (long)(n0 + n) * EMB + kc + kp);
      *(short8*)((char*)Bs + swz(n, kp * 2)) = pack8(src[0], src[1]);
      *(short8*)((char*)Bs + swz(n, kp * 2 + 16)) = pack8(src[2], src[3]);
    }
    __syncthreads();

    int arow = w * 16 + lr;
    short8 a0 = *(short8*)((char*)As + swz(arow, g * 16));
    short8 a1 = *(short8*)((char*)As + swz(arow, 64 + g * 16));
#pragma unroll
    for (int nt = 0; nt < 8; ++nt) {
      int n = nt * 16 + lr;
      short8 b0 = *(short8*)((char*)Bs + swz(n, g * 16));
      short8 b1 = *(short8*)((char*)Bs + swz(n, 64 + g * 16));
      // swapped: C[n][m] -> lane holds n = nt*16+4g+{0..3}, m = w*16+lr
      acc[nt] = __builtin_amdgcn_mfma_f32_16x16x32_bf16(b0, a0, acc[nt], 0, 0, 0);
      acc[nt] = __builtin_amdgcn_mfma_f32_16x16x32_bf16(b1, a1, acc[nt], 0, 0, 0);
    }
    __syncthreads();
  }

  const int mrow = m0 + w * 16 + lr;
#pragma unroll
  for (int nt = 0; nt < 8; ++nt) {
    float4 bias = *(const float4*)(bu + n0 + nt * 16 + 4 * g);
    float4 o;
    o.x = acc[nt][0] + bias.x;
    o.y = acc[nt][1] + bias.y;
    o.z = acc[nt][2] + bias.z;
    o.w = acc[nt][3] + bias.w;
    *(float4*)(out + (long)mrow * EMB + n0 + nt * 16 + 4 * g) = o;
  }
}

extern "C" void kernel_launch(void* const* d_in, const int* in_sizes, int n_in,
                              void* d_out, int out_size, void* d_ws, size_t ws_size,
                              hipStream_t stream) {
  const float* x  = (const float*)d_in[0];
  const float* Wq = (const float*)d_in[1];
  const float* Wk = (const float*)d_in[2];
  const float* Wv = (const float*)d_in[3];
  const float* Wu = (const float*)d_in[4];
  const float* bu = (const float*)d_in[5];
  float* out = (float*)d_out;

  const long per = (long)BH * T * 64;
  short* q_ws  = (short*)d_ws;
  short* k_ws  = q_ws + per;
  short* vt_ws = k_ws + per;   // [bh][d][t''] (key-permuted within 32-blocks)
  short* o_ws  = vt_ws + per;  // [8192][512] bf16

  qkv_kernel<<<512, 256, 0, stream>>>(x, Wq, Wk, Wv, q_ws, k_ws, vt_ws);
  attn_kernel<<<dim3(T / 128, BH), 256, 0, stream>>>(q_ws, k_ws, vt_ws, o_ws);
  proj_kernel<<<dim3(BATCH * T / 64, EMB / 128), 256, 0, stream>>>(o_ws, Wu, bu, out);
}